// Round 1
// baseline (150.385 us; speedup 1.0000x reference)
//
#include <hip/hip_runtime.h>

#define B_    16
#define NL    21
#define NG    42
#define ZW    64
#define HID   1024
#define DECW  64
#define IMG   128
#define NOUT  12288   // 3*64*64
#define MROWS 336     // B_*NL
#define MPAD  384

typedef __bf16 bf16x8 __attribute__((ext_vector_type(8)));
typedef float f32x4 __attribute__((ext_vector_type(4)));
typedef unsigned short ushort8v __attribute__((ext_vector_type(8)));
typedef unsigned short ushort4v __attribute__((ext_vector_type(4)));

static __device__ __forceinline__ unsigned short f2bf(float f) {
    union { float f; unsigned int u; } v; v.f = f;
    unsigned int r = v.u + 0x7fffu + ((v.u >> 16) & 1u);  // RNE
    return (unsigned short)(r >> 16);
}

// ---------------------------------------------------------------------------
// K0: transpose-convert w2 (1024 x 12288 f32, K-major) -> w2t (12288 x 1024 bf16, k contiguous)
// ---------------------------------------------------------------------------
__global__ __launch_bounds__(256) void k0_w2_transpose(const float* __restrict__ w2,
                                                       unsigned short* __restrict__ w2t) {
    __shared__ float tile[64][65];   // +1 pad: conflict-free column reads
    const int nt = blockIdx.x;       // 0..191
    const int kt = blockIdx.y;       // 0..15
    const int t  = threadIdx.x;
    const int n0 = nt * 64, k0 = kt * 64;
    #pragma unroll
    for (int i = 0; i < 4; ++i) {
        int lin = i * 256 + t;           // 1024 float4 = 4096 floats
        int kr  = lin >> 4;
        int nc  = (lin & 15) << 2;
        float4 v = *reinterpret_cast<const float4*>(w2 + (size_t)(k0 + kr) * NOUT + n0 + nc);
        tile[kr][nc + 0] = v.x; tile[kr][nc + 1] = v.y;
        tile[kr][nc + 2] = v.z; tile[kr][nc + 3] = v.w;
    }
    __syncthreads();
    #pragma unroll
    for (int i = 0; i < 4; ++i) {
        int lin = i * 256 + t;
        int nc  = lin >> 4;              // output row (n)
        int kc  = (lin & 15) << 2;       // 4 k elements
        ushort4v r;
        r.x = f2bf(tile[kc + 0][nc]);
        r.y = f2bf(tile[kc + 1][nc]);
        r.z = f2bf(tile[kc + 2][nc]);
        r.w = f2bf(tile[kc + 3][nc]);
        *reinterpret_cast<ushort4v*>(w2t + (size_t)(n0 + nc) * HID + k0 + kc) = r;
    }
}

// ---------------------------------------------------------------------------
// K1: h[r] = relu(z_what[r] @ w1 + b1), r in [0,384), rows >=336 zero-padded. bf16 out.
// ---------------------------------------------------------------------------
__global__ __launch_bounds__(256) void k1_h(const float* __restrict__ z_what,
                                            const float* __restrict__ w1,
                                            const float* __restrict__ b1,
                                            unsigned short* __restrict__ h) {
    const int r = blockIdx.x, t = threadIdx.x;
    if (r >= MROWS) {
        #pragma unroll
        for (int i = 0; i < 4; ++i) h[(size_t)r * HID + t + i * 256] = 0;
        return;
    }
    __shared__ float zs[ZW];
    if (t < ZW) zs[t] = z_what[(size_t)r * ZW + t];
    __syncthreads();
    float acc[4];
    #pragma unroll
    for (int i = 0; i < 4; ++i) acc[i] = b1[t + i * 256];
    for (int k = 0; k < ZW; ++k) {
        float z = zs[k];
        const float* wr = w1 + (size_t)k * HID + t;
        acc[0] = fmaf(z, wr[0],   acc[0]);
        acc[1] = fmaf(z, wr[256], acc[1]);
        acc[2] = fmaf(z, wr[512], acc[2]);
        acc[3] = fmaf(z, wr[768], acc[3]);
    }
    #pragma unroll
    for (int i = 0; i < 4; ++i)
        h[(size_t)r * HID + t + i * 256] = f2bf(acc[i] > 0.f ? acc[i] : 0.f);
}

// ---------------------------------------------------------------------------
// K3: per (b,n): softmax weight over masked z_depth + affine sampling params
// params stride 8 floats: {wn, Ax, Bx, Ay, By, ridx(bitcast int), -, -}
// ---------------------------------------------------------------------------
__global__ void k3_params(const float* __restrict__ z_where,
                          const float* __restrict__ z_depth,
                          const int* __restrict__ z_present,
                          const int* __restrict__ indices,
                          float* __restrict__ params) {
    const int b = blockIdx.x, t = threadIdx.x;   // block = 64 = 1 wave
    const bool valid = t < NG;
    int idx  = valid ? indices[t] : 0;
    int pres = valid ? z_present[b * NG + t] : 0;
    float zd = z_depth[b * NL + idx];
    const bool on = valid && (pres == 1);
    float val = on ? zd : -__builtin_inff();
    float m = val;
    #pragma unroll
    for (int off = 32; off; off >>= 1) m = fmaxf(m, __shfl_xor(m, off));
    float e = on ? __expf(val - m) : 0.f;
    float s = e;
    #pragma unroll
    for (int off = 32; off; off >>= 1) s += __shfl_xor(s, off);
    if (valid) {
        float wn = e / s;
        const float* zw = z_where + (size_t)(b * NG + t) * 4;
        float cx = zw[0], cy = zw[1], ww = zw[2], hh = zw[3];
        float wm = fmaxf(ww, 1e-6f), hm = fmaxf(hh, 1e-6f);
        float Ax = 32.f / wm, Ay = 32.f / hm;
        float Bx = 31.5f - (2.f * cx - 1.f) * Ax;
        float By = 31.5f - (2.f * cy - 1.f) * Ay;
        float* p = params + (size_t)(b * NG + t) * 8;
        p[0] = wn; p[1] = Ax; p[2] = Bx; p[3] = Ay; p[4] = By;
        p[5] = __int_as_float(b * NL + idx);
    }
}

// ---------------------------------------------------------------------------
// K2: dec = sigmoid(h @ w2 + b2).  M=384(pad) K=1024 N=12288, bf16 MFMA 16x16x32.
// BM=64 BN=128 BK=64, 4 waves (wave tile 32x64). XOR-swizzled LDS (G4).
// ---------------------------------------------------------------------------
__global__ __launch_bounds__(256) void k2_gemm(const unsigned short* __restrict__ h,
                                               const unsigned short* __restrict__ w2t,
                                               const float* __restrict__ b2,
                                               float* __restrict__ dec) {
    __shared__ unsigned short As[64 * 64];    // [row][k], swizzled: byte ^= (row&7)<<4
    __shared__ unsigned short Bs[128 * 64];   // [col][k], swizzled
    const int t    = threadIdx.x;
    const int bn   = blockIdx.x;              // 0..95
    const int bm   = blockIdx.y;              // 0..5
    const int row0 = bm * 64, col0 = bn * 128;
    const int lane = t & 63, wid = t >> 6;
    const int wr = (wid >> 1) * 32, wc = (wid & 1) * 64;

    f32x4 acc[2][4];
    const f32x4 zero = {0.f, 0.f, 0.f, 0.f};
    #pragma unroll
    for (int m = 0; m < 2; ++m)
        #pragma unroll
        for (int n = 0; n < 4; ++n) acc[m][n] = zero;

    for (int k0 = 0; k0 < HID; k0 += 64) {
        // stage A: 64 rows x 128B
        #pragma unroll
        for (int rnd = 0; rnd < 2; ++rnd) {
            int ci  = rnd * 256 + t;
            int row = ci >> 3;
            int bir = (ci & 7) << 4;          // byte in row
            ushort8v v = *reinterpret_cast<const ushort8v*>(
                h + (size_t)(row0 + row) * HID + k0 + (bir >> 1));
            int dst = row * 128 + (bir ^ ((row & 7) << 4));
            *reinterpret_cast<ushort8v*>(reinterpret_cast<char*>(As) + dst) = v;
        }
        // stage B: 128 cols x 128B
        #pragma unroll
        for (int rnd = 0; rnd < 4; ++rnd) {
            int ci  = rnd * 256 + t;
            int col = ci >> 3;
            int bir = (ci & 7) << 4;
            ushort8v v = *reinterpret_cast<const ushort8v*>(
                w2t + (size_t)(col0 + col) * HID + k0 + (bir >> 1));
            int dst = col * 128 + (bir ^ ((col & 7) << 4));
            *reinterpret_cast<ushort8v*>(reinterpret_cast<char*>(Bs) + dst) = v;
        }
        __syncthreads();
        #pragma unroll
        for (int ks = 0; ks < 2; ++ks) {
            const int kb = ks * 64 + ((lane >> 4) << 4);  // byte offset of this lane's 8 bf16
            bf16x8 a[2], bb[4];
            #pragma unroll
            for (int m = 0; m < 2; ++m) {
                int row = wr + m * 16 + (lane & 15);
                int ad  = row * 128 + (kb ^ ((row & 7) << 4));
                a[m] = *reinterpret_cast<const bf16x8*>(reinterpret_cast<const char*>(As) + ad);
            }
            #pragma unroll
            for (int n = 0; n < 4; ++n) {
                int col = wc + n * 16 + (lane & 15);
                int ad  = col * 128 + (kb ^ ((col & 7) << 4));
                bb[n] = *reinterpret_cast<const bf16x8*>(reinterpret_cast<const char*>(Bs) + ad);
            }
            #pragma unroll
            for (int m = 0; m < 2; ++m)
                #pragma unroll
                for (int n = 0; n < 4; ++n)
                    acc[m][n] = __builtin_amdgcn_mfma_f32_16x16x32_bf16(a[m], bb[n], acc[m][n], 0, 0, 0);
        }
        __syncthreads();
    }
    // epilogue: bias + sigmoid.  C/D: col=lane&15, row=(lane>>4)*4+reg  [measured m89/m91]
    const int rbase = row0 + wr + ((lane >> 4) << 2);
    const int cbase = col0 + wc + (lane & 15);
    #pragma unroll
    for (int n = 0; n < 4; ++n) {
        int col = cbase + n * 16;
        float bias = b2[col];
        #pragma unroll
        for (int m = 0; m < 2; ++m) {
            #pragma unroll
            for (int j = 0; j < 4; ++j) {
                int row = rbase + m * 16 + j;
                float v = acc[m][n][j] + bias;
                dec[(size_t)row * NOUT + col] = 1.f / (1.f + __expf(-v));
            }
        }
    }
}

// ---------------------------------------------------------------------------
// K4: fused bilinear sampling + softmax-weighted composite.
// One thread = one (b,y,x), 3 channels. bbox skip per glimpse.
// ---------------------------------------------------------------------------
__global__ __launch_bounds__(256) void k4_composite(const float* __restrict__ dec,
                                                    const float* __restrict__ params,
                                                    float* __restrict__ out) {
    __shared__ float P[NG * 6];
    const int b    = blockIdx.x >> 6;
    const int tile = blockIdx.x & 63;
    const int t    = threadIdx.x;
    if (t < NG * 6) {
        int n = t / 6, sl = t % 6;
        P[t] = params[(size_t)(b * NG + n) * 8 + sl];
    }
    __syncthreads();
    const int x = ((tile & 7) << 4) + (t & 15);
    const int y = ((tile >> 3) << 4) + (t >> 4);
    const float xt = (x + 0.5f) * (1.f / 64.f) - 1.f;
    const float yt = (y + 0.5f) * (1.f / 64.f) - 1.f;
    float a0 = 0.f, a1 = 0.f, a2 = 0.f;
    for (int n = 0; n < NG; ++n) {
        float wn = P[n * 6 + 0];
        if (wn == 0.f) continue;                       // masked-out glimpse
        float px = fmaf(xt, P[n * 6 + 1], P[n * 6 + 2]);
        float py = fmaf(yt, P[n * 6 + 3], P[n * 6 + 4]);
        if (!(px > -1.f && px < 64.f && py > -1.f && py < 64.f)) continue;
        float x0f = floorf(px), y0f = floorf(py);
        float wx = px - x0f, wy = py - y0f;
        int x0 = (int)x0f, y0 = (int)y0f;
        int x1 = x0 + 1, y1 = y0 + 1;
        bool vx0 = x0 >= 0, vx1 = x1 < 64, vy0 = y0 >= 0, vy1 = y1 < 64;
        int ridx = __float_as_int(P[n * 6 + 5]);
        const float* base = dec + (size_t)ridx * NOUT;
        float w00 = (1.f - wx) * (1.f - wy), w10 = wx * (1.f - wy);
        float w01 = (1.f - wx) * wy,         w11 = wx * wy;
        int o00 = y0 * 64 + x0, o10 = y0 * 64 + x1;
        int o01 = y1 * 64 + x0, o11 = y1 * 64 + x1;
        #pragma unroll
        for (int c = 0; c < 3; ++c) {
            const float* cb = base + c * 4096;
            float v00 = (vx0 && vy0) ? cb[o00] : 0.f;
            float v10 = (vx1 && vy0) ? cb[o10] : 0.f;
            float v01 = (vx0 && vy1) ? cb[o01] : 0.f;
            float v11 = (vx1 && vy1) ? cb[o11] : 0.f;
            float s = v00 * w00 + v10 * w10 + v01 * w01 + v11 * w11;
            if      (c == 0) a0 = fmaf(wn, s, a0);
            else if (c == 1) a1 = fmaf(wn, s, a1);
            else             a2 = fmaf(wn, s, a2);
        }
    }
    out[((size_t)(b * 3 + 0) * IMG + y) * IMG + x] = a0;
    out[((size_t)(b * 3 + 1) * IMG + y) * IMG + x] = a1;
    out[((size_t)(b * 3 + 2) * IMG + y) * IMG + x] = a2;
}

// ---------------------------------------------------------------------------
extern "C" void kernel_launch(void* const* d_in, const int* in_sizes, int n_in,
                              void* d_out, int out_size, void* d_ws, size_t ws_size,
                              hipStream_t stream) {
    const float* z_what   = (const float*)d_in[0];
    const float* z_where  = (const float*)d_in[1];
    const float* z_depth  = (const float*)d_in[2];
    const float* w1       = (const float*)d_in[3];
    const float* b1       = (const float*)d_in[4];
    const float* w2       = (const float*)d_in[5];
    const float* b2       = (const float*)d_in[6];
    const int*   z_present= (const int*)d_in[7];
    const int*   indices  = (const int*)d_in[8];
    float* out = (float*)d_out;

    char* ws = (char*)d_ws;
    unsigned short* w2t = (unsigned short*)ws;                              // 25,165,824 B
    unsigned short* h   = (unsigned short*)(ws + 25165824);                 //    786,432 B
    float*          dec = (float*)(ws + 25165824 + 786432);                 // 18,874,368 B
    float*       params = (float*)(ws + 25165824 + 786432 + 18874368);      //     21,504 B

    hipLaunchKernelGGL(k0_w2_transpose, dim3(192, 16), dim3(256), 0, stream, w2, w2t);
    hipLaunchKernelGGL(k1_h,            dim3(MPAD),    dim3(256), 0, stream, z_what, w1, b1, h);
    hipLaunchKernelGGL(k3_params,       dim3(B_),      dim3(64),  0, stream, z_where, z_depth, z_present, indices, params);
    hipLaunchKernelGGL(k2_gemm,         dim3(96, 6),   dim3(256), 0, stream, h, w2t, b2, dec);
    hipLaunchKernelGGL(k4_composite,    dim3(1024),    dim3(256), 0, stream, dec, params, out);
}

// Round 4
// 145.301 us; speedup vs baseline: 1.0350x; 1.0350x over previous
//
#include <hip/hip_runtime.h>

#define B_    16
#define NL    21
#define NG    42
#define ZW    64
#define HID   1024
#define IMG   128
#define NOUT  12288   // 3*64*64
#define MROWS 336     // B_*NL
#define MPAD  384

typedef __bf16 bf16x8 __attribute__((ext_vector_type(8)));
typedef float f32x4 __attribute__((ext_vector_type(4)));
typedef unsigned short ushort8v __attribute__((ext_vector_type(8)));
typedef unsigned short ushort4v __attribute__((ext_vector_type(4)));

static __device__ __forceinline__ unsigned short f2bf(float f) {
    union { float f; unsigned int u; } v; v.f = f;
    unsigned int r = v.u + 0x7fffu + ((v.u >> 16) & 1u);  // RNE
    return (unsigned short)(r >> 16);
}

// global -> LDS direct copy, 16B per lane (dest must be wave-uniform base + lane*16)
static __device__ __forceinline__ void gload_lds16(const void* g, void* l) {
    __builtin_amdgcn_global_load_lds(
        (const __attribute__((address_space(1))) void*)g,
        (__attribute__((address_space(3))) void*)l,
        16, 0, 0);
}

// ---------------------------------------------------------------------------
// K0: transpose-convert w2 (1024 x 12288 f32) -> w2t (12288 x 1024 bf16, k-contig)
// PRE-SWIZZLED: within each 64-k segment, element index k -> k ^ ((col&7)<<3)
// so K2 can stage linearly with global_load_lds and XOR only on ds_read.
// ---------------------------------------------------------------------------
__global__ __launch_bounds__(256) void k0_w2_transpose(const float* __restrict__ w2,
                                                       unsigned short* __restrict__ w2t) {
    __shared__ float tile[64][65];
    const int nt = blockIdx.x;       // 0..191
    const int kt = blockIdx.y;       // 0..15
    const int t  = threadIdx.x;
    const int n0 = nt * 64, k0 = kt * 64;
    #pragma unroll
    for (int i = 0; i < 4; ++i) {
        int lin = i * 256 + t;
        int kr  = lin >> 4;
        int nc  = (lin & 15) << 2;
        float4 v = *reinterpret_cast<const float4*>(w2 + (size_t)(k0 + kr) * NOUT + n0 + nc);
        tile[kr][nc + 0] = v.x; tile[kr][nc + 1] = v.y;
        tile[kr][nc + 2] = v.z; tile[kr][nc + 3] = v.w;
    }
    __syncthreads();
    #pragma unroll
    for (int i = 0; i < 4; ++i) {
        int lin = i * 256 + t;
        int nc  = lin >> 4;              // col within tile
        int kc  = (lin & 15) << 2;       // 4 k elements (rel. to k0)
        ushort4v r;
        r.x = f2bf(tile[kc + 0][nc]);
        r.y = f2bf(tile[kc + 1][nc]);
        r.z = f2bf(tile[kc + 2][nc]);
        r.w = f2bf(tile[kc + 3][nc]);
        int kc_s = kc ^ ((nc & 7) << 3);                     // swizzle (4-aligned group intact)
        *reinterpret_cast<ushort4v*>(w2t + (size_t)(n0 + nc) * HID + k0 + kc_s) = r;
    }
}

// ---------------------------------------------------------------------------
// K1: h[r] = relu(z_what[r] @ w1 + b1), rows >=336 zero. bf16, PRE-SWIZZLED like w2t.
// ---------------------------------------------------------------------------
__global__ __launch_bounds__(256) void k1_h(const float* __restrict__ z_what,
                                            const float* __restrict__ w1,
                                            const float* __restrict__ b1,
                                            unsigned short* __restrict__ h) {
    const int r = blockIdx.x, t = threadIdx.x;
    const int sw = (r & 7) << 3;
    if (r >= MROWS) {
        #pragma unroll
        for (int i = 0; i < 4; ++i) {
            int k = t + i * 256;
            h[(size_t)r * HID + ((k & ~63) | ((k & 63) ^ sw))] = 0;
        }
        return;
    }
    __shared__ float zs[ZW];
    if (t < ZW) zs[t] = z_what[(size_t)r * ZW + t];
    __syncthreads();
    float acc[4];
    #pragma unroll
    for (int i = 0; i < 4; ++i) acc[i] = b1[t + i * 256];
    for (int k = 0; k < ZW; ++k) {
        float z = zs[k];
        const float* wr = w1 + (size_t)k * HID + t;
        acc[0] = fmaf(z, wr[0],   acc[0]);
        acc[1] = fmaf(z, wr[256], acc[1]);
        acc[2] = fmaf(z, wr[512], acc[2]);
        acc[3] = fmaf(z, wr[768], acc[3]);
    }
    #pragma unroll
    for (int i = 0; i < 4; ++i) {
        int k = t + i * 256;
        h[(size_t)r * HID + ((k & ~63) | ((k & 63) ^ sw))] =
            f2bf(acc[i] > 0.f ? acc[i] : 0.f);
    }
}

// ---------------------------------------------------------------------------
// K3: softmax weight + affine params + integer pixel bbox (1-px padded).
// params stride 16 floats: {wn, Ax, Bx, Ay, By, ridx, xlo, xhi, ylo, yhi, ...}
// ---------------------------------------------------------------------------
__global__ void k3_params(const float* __restrict__ z_where,
                          const float* __restrict__ z_depth,
                          const int* __restrict__ z_present,
                          const int* __restrict__ indices,
                          float* __restrict__ params) {
    const int b = blockIdx.x, t = threadIdx.x;   // 1 wave
    const bool valid = t < NG;
    int idx  = valid ? indices[t] : 0;
    int pres = valid ? z_present[b * NG + t] : 0;
    float zd = z_depth[b * NL + idx];
    const bool on = valid && (pres == 1);
    float val = on ? zd : -__builtin_inff();
    float m = val;
    #pragma unroll
    for (int off = 32; off; off >>= 1) m = fmaxf(m, __shfl_xor(m, off));
    float e = on ? __expf(val - m) : 0.f;
    float s = e;
    #pragma unroll
    for (int off = 32; off; off >>= 1) s += __shfl_xor(s, off);
    if (valid) {
        float wn = e / s;
        const float* zw = z_where + (size_t)(b * NG + t) * 4;
        float cx = zw[0], cy = zw[1], ww = zw[2], hh = zw[3];
        float wm = fmaxf(ww, 1e-6f), hm = fmaxf(hh, 1e-6f);
        float Ax = 32.f / wm, Ay = 32.f / hm;
        float Bx = 31.5f - (2.f * cx - 1.f) * Ax;
        float By = 31.5f - (2.f * cy - 1.f) * Ay;
        // pixel bbox: px(x) in (-1,64), px = Ax*xt+Bx, xt=(x+.5)/64-1, padded 1px
        float xlof = ((-1.f - Bx) / Ax + 1.f) * 64.f - 0.5f;
        float xhif = (( 64.f - Bx) / Ax + 1.f) * 64.f - 0.5f;
        float ylof = ((-1.f - By) / Ay + 1.f) * 64.f - 0.5f;
        float yhif = (( 64.f - By) / Ay + 1.f) * 64.f - 0.5f;
        int xlo = max(0,   (int)floorf(xlof));
        int xhi = min(128, (int)floorf(xhif) + 2);
        int ylo = max(0,   (int)floorf(ylof));
        int yhi = min(128, (int)floorf(yhif) + 2);
        float* p = params + (size_t)(b * NG + t) * 16;
        p[0] = wn; p[1] = Ax; p[2] = Bx; p[3] = Ay; p[4] = By;
        p[5] = __int_as_float(b * NL + idx);
        p[6] = __int_as_float(xlo); p[7] = __int_as_float(xhi);
        p[8] = __int_as_float(ylo); p[9] = __int_as_float(yhi);
    }
}

// ---------------------------------------------------------------------------
// K2: dec = sigmoid(h @ w2t^T + b2). M=384 K=1024 N=12288.
// BM=128 BN=128 BK=64, 4 waves (64x64 wave tile), global_load_lds staging,
// double-buffered LDS (64KB), 2-phase schedule, XOR-swizzled ds_read.
// ---------------------------------------------------------------------------
__global__ __launch_bounds__(256) void k2_gemm(const unsigned short* __restrict__ h,
                                               const unsigned short* __restrict__ w2t,
                                               const float* __restrict__ b2,
                                               float* __restrict__ dec) {
    __shared__ char smem[65536];   // [buf][A:16K | B:16K]
    const int t    = threadIdx.x;
    const int bn   = blockIdx.x;              // 0..95
    const int bm   = blockIdx.y;              // 0..2
    const int row0 = bm * 128, col0 = bn * 128;
    const int lane = t & 63, wid = t >> 6;
    const int wr = (wid >> 1) * 64, wc = (wid & 1) * 64;

    f32x4 acc[4][4];
    const f32x4 zero = {0.f, 0.f, 0.f, 0.f};
    #pragma unroll
    for (int m = 0; m < 4; ++m)
        #pragma unroll
        for (int n = 0; n < 4; ++n) acc[m][n] = zero;

    const char* hB = (const char*)h   + ((size_t)row0 << 11);  // row stride 2048B
    const char* wB = (const char*)w2t + ((size_t)col0 << 11);

    // stage k-tile kt into buffer buf: A chunks then B chunks, linear LDS
    #define STAGE(kt_, buf_)                                                        \
        do {                                                                        \
            int kby = (kt_) << 7; /* 64 k * 2B */                                   \
            char* ldsA = smem + (buf_) * 32768;                                     \
            char* ldsB = ldsA + 16384;                                              \
            _Pragma("unroll")                                                       \
            for (int r_ = 0; r_ < 4; ++r_) {                                        \
                int ci  = r_ * 256 + t;                                             \
                int row = ci >> 3, kc = ci & 7;                                     \
                gload_lds16(hB + ((size_t)row << 11) + kby + (kc << 4),             \
                            ldsA + ci * 16);                                        \
                gload_lds16(wB + ((size_t)row << 11) + kby + (kc << 4),             \
                            ldsB + ci * 16);                                        \
            }                                                                       \
        } while (0)

    #define COMPUTE(buf_)                                                           \
        do {                                                                        \
            const char* Ab = smem + (buf_) * 32768;                                 \
            const char* Bb = Ab + 16384;                                            \
            _Pragma("unroll")                                                       \
            for (int ks = 0; ks < 2; ++ks) {                                        \
                int kb = ks * 64 + ((lane >> 4) << 4);                              \
                bf16x8 a[4], bb[4];                                                 \
                _Pragma("unroll")                                                   \
                for (int m = 0; m < 4; ++m) {                                       \
                    int row = wr + m * 16 + (lane & 15);                            \
                    a[m] = *reinterpret_cast<const bf16x8*>(                        \
                        Ab + row * 128 + (kb ^ ((row & 7) << 4)));                  \
                }                                                                   \
                _Pragma("unroll")                                                   \
                for (int n = 0; n < 4; ++n) {                                       \
                    int col = wc + n * 16 + (lane & 15);                            \
                    bb[n] = *reinterpret_cast<const bf16x8*>(                       \
                        Bb + col * 128 + (kb ^ ((col & 7) << 4)));                  \
                }                                                                   \
                _Pragma("unroll")                                                   \
                for (int m = 0; m < 4; ++m)                                         \
                    _Pragma("unroll")                                               \
                    for (int n = 0; n < 4; ++n)                                     \
                        acc[m][n] = __builtin_amdgcn_mfma_f32_16x16x32_bf16(        \
                            a[m], bb[n], acc[m][n], 0, 0, 0);                       \
            }                                                                       \
        } while (0)

    STAGE(0, 0);
    __syncthreads();
    int cur = 0;
    for (int kt = 1; kt < 16; ++kt) {
        STAGE(kt, cur ^ 1);
        COMPUTE(cur);
        __syncthreads();
        cur ^= 1;
    }
    COMPUTE(cur);

    // epilogue: bias + sigmoid.  C/D: col=lane&15, row=(lane>>4)*4+reg
    const int rbase = row0 + wr + ((lane >> 4) << 2);
    const int cbase = col0 + wc + (lane & 15);
    #pragma unroll
    for (int n = 0; n < 4; ++n) {
        int col = cbase + n * 16;
        float bias = b2[col];
        #pragma unroll
        for (int m = 0; m < 4; ++m) {
            #pragma unroll
            for (int j = 0; j < 4; ++j) {
                int row = rbase + m * 16 + j;
                float v = acc[m][n][j] + bias;
                dec[(size_t)row * NOUT + col] = 1.f / (1.f + __expf(-v));
            }
        }
    }
    #undef STAGE
    #undef COMPUTE
}

// ---------------------------------------------------------------------------
// K4: per-block (16x16 tile) glimpse compaction, then fused bilinear+composite.
// ---------------------------------------------------------------------------
__global__ __launch_bounds__(256) void k4_composite(const float* __restrict__ dec,
                                                    const float* __restrict__ params,
                                                    float* __restrict__ out) {
    __shared__ float Pc[NG * 6];
    __shared__ int s_cnt;
    const int b    = blockIdx.x >> 6;
    const int tile = blockIdx.x & 63;
    const int tx0 = (tile & 7) << 4, ty0 = (tile >> 3) << 4;
    const int t    = threadIdx.x;
    if (t < 64) {
        bool pass = false;
        float wn = 0.f, Ax = 0.f, Bx = 0.f, Ay = 0.f, By = 0.f, ridx = 0.f;
        if (t < NG) {
            const float* p = params + (size_t)(b * NG + t) * 16;
            wn = p[0];
            if (wn != 0.f) {
                int xlo = __float_as_int(p[6]), xhi = __float_as_int(p[7]);
                int ylo = __float_as_int(p[8]), yhi = __float_as_int(p[9]);
                if (xlo < tx0 + 16 && xhi > tx0 && ylo < ty0 + 16 && yhi > ty0) {
                    pass = true; Ax = p[1]; Bx = p[2]; Ay = p[3]; By = p[4]; ridx = p[5];
                }
            }
        }
        unsigned long long mask = __ballot(pass);
        if (pass) {
            int slot = __popcll(mask & ((1ull << t) - 1ull));
            float* q = Pc + slot * 6;
            q[0] = wn; q[1] = Ax; q[2] = Bx; q[3] = Ay; q[4] = By; q[5] = ridx;
        }
        if (t == 0) s_cnt = __popcll(mask);
    }
    __syncthreads();
    const int cnt = s_cnt;
    const int x = tx0 + (t & 15);
    const int y = ty0 + (t >> 4);
    const float xt = (x + 0.5f) * (1.f / 64.f) - 1.f;
    const float yt = (y + 0.5f) * (1.f / 64.f) - 1.f;
    float a0 = 0.f, a1 = 0.f, a2 = 0.f;
    for (int i = 0; i < cnt; ++i) {
        const float* q = Pc + i * 6;
        float wn = q[0];
        float px = fmaf(xt, q[1], q[2]);
        float py = fmaf(yt, q[3], q[4]);
        if (!(px > -1.f && px < 64.f && py > -1.f && py < 64.f)) continue;
        float x0f = floorf(px), y0f = floorf(py);
        float wx = px - x0f, wy = py - y0f;
        int x0 = (int)x0f, y0 = (int)y0f;
        int x1 = x0 + 1, y1 = y0 + 1;
        bool vx0 = x0 >= 0, vx1 = x1 < 64, vy0 = y0 >= 0, vy1 = y1 < 64;
        int ridx = __float_as_int(q[5]);
        const float* base = dec + (size_t)ridx * NOUT;
        float w00 = (1.f - wx) * (1.f - wy), w10 = wx * (1.f - wy);
        float w01 = (1.f - wx) * wy,         w11 = wx * wy;
        int o00 = y0 * 64 + x0, o10 = y0 * 64 + x1;
        int o01 = y1 * 64 + x0, o11 = y1 * 64 + x1;
        #pragma unroll
        for (int c = 0; c < 3; ++c) {
            const float* cb = base + c * 4096;
            float v00 = (vx0 && vy0) ? cb[o00] : 0.f;
            float v10 = (vx1 && vy0) ? cb[o10] : 0.f;
            float v01 = (vx0 && vy1) ? cb[o01] : 0.f;
            float v11 = (vx1 && vy1) ? cb[o11] : 0.f;
            float sv = v00 * w00 + v10 * w10 + v01 * w01 + v11 * w11;
            if      (c == 0) a0 = fmaf(wn, sv, a0);
            else if (c == 1) a1 = fmaf(wn, sv, a1);
            else             a2 = fmaf(wn, sv, a2);
        }
    }
    out[((size_t)(b * 3 + 0) * IMG + y) * IMG + x] = a0;
    out[((size_t)(b * 3 + 1) * IMG + y) * IMG + x] = a1;
    out[((size_t)(b * 3 + 2) * IMG + y) * IMG + x] = a2;
}

// ---------------------------------------------------------------------------
extern "C" void kernel_launch(void* const* d_in, const int* in_sizes, int n_in,
                              void* d_out, int out_size, void* d_ws, size_t ws_size,
                              hipStream_t stream) {
    const float* z_what   = (const float*)d_in[0];
    const float* z_where  = (const float*)d_in[1];
    const float* z_depth  = (const float*)d_in[2];
    const float* w1       = (const float*)d_in[3];
    const float* b1       = (const float*)d_in[4];
    const float* w2       = (const float*)d_in[5];
    const float* b2       = (const float*)d_in[6];
    const int*   z_present= (const int*)d_in[7];
    const int*   indices  = (const int*)d_in[8];
    float* out = (float*)d_out;

    char* ws = (char*)d_ws;
    unsigned short* w2t = (unsigned short*)ws;                              // 25,165,824 B
    unsigned short* h   = (unsigned short*)(ws + 25165824);                 //    786,432 B
    float*          dec = (float*)(ws + 25165824 + 786432);                 // 18,874,368 B
    float*       params = (float*)(ws + 25165824 + 786432 + 18874368);      //     43,008 B

    hipLaunchKernelGGL(k0_w2_transpose, dim3(192, 16), dim3(256), 0, stream, w2, w2t);
    hipLaunchKernelGGL(k1_h,            dim3(MPAD),    dim3(256), 0, stream, z_what, w1, b1, h);
    hipLaunchKernelGGL(k3_params,       dim3(B_),      dim3(64),  0, stream, z_where, z_depth, z_present, indices, params);
    hipLaunchKernelGGL(k2_gemm,         dim3(96, 3),   dim3(256), 0, stream, h, w2t, b2, dec);
    hipLaunchKernelGGL(k4_composite,    dim3(1024),    dim3(256), 0, stream, dec, params, out);
}